// Round 4
// baseline (122.402 us; speedup 1.0000x reference)
//
#include <hip/hip_runtime.h>

// out[b,m,d,f] = sum_{a,c} x[b,m,a,f] * y[b,m,c,f] * cgc[a,d,c]
// Round 10: occupancy experiment — 8 waves/SIMD (was 4 in R6/R8/R9).
//
// All prior structures (LDS-DMA staged, scalar direct, paired dwordx2) land
// at the same ~23us inferred kernel time (~4.3 TB/s vs 6.3 achievable), so
// instruction-shape is not the limiter. The only never-varied axis is
// occupancy: all held >=100 VGPR (32-VGPR resident wfrag) -> 4 waves/SIMD.
// This version targets <=64 VGPR for the 8-waves/SIMD cliff (m69):
//   - f-split: each wave owns (bm, 64-col f-half): 8192 waves, no reduction
//   - W streamed from cgc per MFMA (cgc = 16KB, L1-resident; frees 32 VGPR)
//   - no explicit prefetch: latency hiding delegated to TLP
// Verified MFMA k-mapping unchanged: A elem j of lane(L,quad) = cgc[a][L][c],
// a = 2t+qh, c = c0+j; B elem j = x[a][f0+L] * y[c0+j][f0+L]; D row=quad*4+r,
// col=L.

typedef __attribute__((ext_vector_type(2))) _Float16 half2v;
typedef __attribute__((ext_vector_type(8))) _Float16 half8;
typedef __attribute__((ext_vector_type(4))) float    floatx4;

#define AA 16
#define FF 128

union H8 { half2v h2[4]; half8 h8; };

// cvt_pkrtz returns a __fp16 ext-vector; bit-cast to the _Float16 vector type
// so downstream arithmetic stays native packed-half (v_pk_mul_f16).
static __device__ __forceinline__ half2v pkrtz(float a, float b) {
    return __builtin_bit_cast(half2v, __builtin_amdgcn_cvt_pkrtz(a, b));
}

__global__ __launch_bounds__(256, 8)
void tpc_mfma_occ8_kernel(const float* __restrict__ x,
                          const float* __restrict__ y,
                          const float* __restrict__ cgc,
                          float* __restrict__ out) {
    const int tid  = threadIdx.x;
    const int w    = tid >> 6;         // wave 0..3
    const int lane = tid & 63;
    const int L    = lane & 15;        // A: m(=d); B: n(=f in tile); D: col
    const int quad = lane >> 4;
    const int qh   = quad >> 1;        // a parity
    const int c0   = (quad & 1) * 8;   // c sub-range

    // wave -> (bm, f-half): 2048 blocks x 2 bm, 2 waves per bm
    const int bm    = blockIdx.x * 2 + (w >> 1);
    const int fbase = (w & 1) * 64;

    const size_t stride = (size_t)(AA * FF);
    const float* xb = x + (size_t)bm * stride + fbase;
    const float* yb = y + (size_t)bm * stride + fbase;
    float*       ob = out + (size_t)bm * stride + fbase;
    // W row base for this lane: cgc[a=qh + 2t][L][c0..c0+7]; +t*512 floats per t
    const float* wbase = cgc + qh * (AA * AA) + L * AA + c0;

#pragma unroll
    for (int g = 0; g < 4; ++g) {
        const int f0 = g * 16 + L;     // this lane's column within the f-half

        // ---- column loads for this 16-col group (HBM) ----
        float xv[8], yv[8];
#pragma unroll
        for (int t = 0; t < 8; ++t)
            xv[t] = xb[(2 * t + qh) * FF + f0];
#pragma unroll
        for (int j = 0; j < 8; ++j)
            yv[j] = yb[(c0 + j) * FF + f0];

        // ---- pack to fp16 ----
        half2v yp[4];
#pragma unroll
        for (int jj = 0; jj < 4; ++jj)
            yp[jj] = pkrtz(yv[2 * jj], yv[2 * jj + 1]);
        half2v xp[8];
#pragma unroll
        for (int t = 0; t < 8; ++t)
            xp[t] = pkrtz(xv[t], xv[t]);   // broadcast x[a][f0] to both halves

        // ---- MFMA over k=256, W streamed from L1-resident cgc ----
        floatx4 acc = {0.f, 0.f, 0.f, 0.f};
#pragma unroll
        for (int t = 0; t < 8; ++t) {
            const float* wp = wbase + t * (2 * AA * AA);
            const floatx4 w0 = *(const floatx4*)(wp);
            const floatx4 w1 = *(const floatx4*)(wp + 4);
            H8 wa;
            wa.h2[0] = pkrtz(w0.x, w0.y);
            wa.h2[1] = pkrtz(w0.z, w0.w);
            wa.h2[2] = pkrtz(w1.x, w1.y);
            wa.h2[3] = pkrtz(w1.z, w1.w);

            H8 b;
            b.h2[0] = xp[t] * yp[0];
            b.h2[1] = xp[t] * yp[1];
            b.h2[2] = xp[t] * yp[2];
            b.h2[3] = xp[t] * yp[3];
            acc = __builtin_amdgcn_mfma_f32_16x16x32_f16(wa.h8, b.h8, acc, 0, 0, 0);
        }

        // ---- stores: 4 rows, 64B per 16-lane quad ----
#pragma unroll
        for (int r = 0; r < 4; ++r) {
            const int row = (quad * 4 + r) * FF;
            ob[row + f0] = acc[r];
        }
    }
}

extern "C" void kernel_launch(void* const* d_in, const int* in_sizes, int n_in,
                              void* d_out, int out_size, void* d_ws, size_t ws_size,
                              hipStream_t stream) {
    const float* x   = (const float*)d_in[0];
    const float* y   = (const float*)d_in[1];
    const float* cgc = (const float*)d_in[2];
    float* out = (float*)d_out;

    // 4096 bm x 2 f-halves = 8192 waves: 2048 blocks x 256 threads.
    // 2048 blocks = exactly 8 blocks/CU co-resident (32 waves/CU).
    hipLaunchKernelGGL(tpc_mfma_occ8_kernel, dim3(2048), dim3(256), 0, stream,
                       x, y, cgc, out);
}

// Round 5
// 110.652 us; speedup vs baseline: 1.1062x; 1.1062x over previous
//
#include <hip/hip_runtime.h>

// out[b,m,d,f] = sum_{a,c} x[b,m,a,f] * y[b,m,c,f] * cgc[a,d,c]
// Round 11: prefetch (R8) + f-half split (R10) + 6 waves/SIMD target.
//
// R10 post-mortem: the (256,8)/64-VGPR cap + L1-streamed W collapsed ILP
// (VGPR=32, serial load->cvt->MFMA chains, 2 TB/s, VALUBusy 9%). This round
// keeps BOTH levers but avoids the collapse:
//   - resident wfrag[8] (32 VGPR) built once per wave  [R10's streaming killed]
//   - single-buffer next-group prefetch into freed raw regs  [R8's pipeline]
//   - f-half split: wave owns (bm, 64 cols) -> raw state halved to 16 regs
//   - natural VGPR ~72 -> 6-7 waves/SIMD at fine-grained allocation;
//     __launch_bounds__(256,6) pressures allocator without starving it
// Theory: compute (~200cy) covers 1/4 of HBM latency; 6 waves x 200cy > 900cy
// latency window -> fully hidden -> BW-bound at last.
//
// Verified MFMA mapping (R3-R10, all passed): A elem j = cgc[2t+qh][L][c0+j],
// B elem j = x[2t+qh][f]*y[c0+j][f], D row=quad*4+r col=L.

typedef __attribute__((ext_vector_type(2))) _Float16 half2v;
typedef __attribute__((ext_vector_type(8))) _Float16 half8;
typedef __attribute__((ext_vector_type(4))) float    floatx4;

#define AA 16
#define FF 128

union H8 { half2v h2[4]; half8 h8; };

static __device__ __forceinline__ half2v pkrtz(float a, float b) {
    return __builtin_bit_cast(half2v, __builtin_amdgcn_cvt_pkrtz(a, b));
}

__global__ __launch_bounds__(256, 6)
void tpc_mfma_occ6_kernel(const float* __restrict__ x,
                          const float* __restrict__ y,
                          const float* __restrict__ cgc,
                          float* __restrict__ out) {
    const int tid  = threadIdx.x;
    const int w    = tid >> 6;         // wave 0..3
    const int lane = tid & 63;
    const int L    = lane & 15;        // A: m(=d); B: n(=f in tile); D: col
    const int quad = lane >> 4;
    const int qh   = quad >> 1;        // a parity
    const int c0   = (quad & 1) * 8;   // c sub-range

    // wave -> (bm, f-half): 2048 blocks x 2 bm, 2 waves per bm
    const int bm    = blockIdx.x * 2 + (w >> 1);
    const int fbase = (w & 1) * 64;

    const size_t stride = (size_t)(AA * FF);
    const float* xb = x + (size_t)bm * stride + fbase;
    const float* yb = y + (size_t)bm * stride + fbase;
    float*       ob = out + (size_t)bm * stride + fbase;

    // ---- issue group-0 x/y loads first (HBM, longest latency) ----
    float xv[8], yv[8];
#pragma unroll
    for (int t = 0; t < 8; ++t)
        xv[t] = xb[(2 * t + qh) * FF + L];
#pragma unroll
    for (int j = 0; j < 8; ++j)
        yv[j] = yb[(c0 + j) * FF + L];

    // ---- W fragments resident (32 VGPR), built once; cgc is L2-resident
    //      and its latency hides under the group-0 HBM loads ----
    half8 wfrag[8];
#pragma unroll
    for (int t = 0; t < 8; ++t) {
        const float* wp = cgc + (2 * t + qh) * (AA * AA) + L * AA + c0;
        const floatx4 w0 = *(const floatx4*)(wp);
        const floatx4 w1 = *(const floatx4*)(wp + 4);
        H8 wa;
        wa.h2[0] = pkrtz(w0.x, w0.y);
        wa.h2[1] = pkrtz(w0.z, w0.w);
        wa.h2[2] = pkrtz(w1.x, w1.y);
        wa.h2[3] = pkrtz(w1.z, w1.w);
        wfrag[t] = wa.h8;
    }

#pragma unroll
    for (int g = 0; g < 4; ++g) {
        // ---- pack current group's columns to fp16 (consumes raw regs) ----
        half2v yp[4];
#pragma unroll
        for (int jj = 0; jj < 4; ++jj)
            yp[jj] = pkrtz(yv[2 * jj], yv[2 * jj + 1]);
        half2v xp[8];
#pragma unroll
        for (int t = 0; t < 8; ++t)
            xp[t] = pkrtz(xv[t], xv[t]);

        // ---- raw regs free: issue next group's loads immediately; MFMA +
        //      stores below plus other waves' issue cover their latency ----
        if (g < 3) {
            const int f1 = (g + 1) * 16 + L;
#pragma unroll
            for (int t = 0; t < 8; ++t)
                xv[t] = xb[(2 * t + qh) * FF + f1];
#pragma unroll
            for (int j = 0; j < 8; ++j)
                yv[j] = yb[(c0 + j) * FF + f1];
        }

        // ---- MFMA over k=256 for this 16-col tile ----
        floatx4 acc = {0.f, 0.f, 0.f, 0.f};
#pragma unroll
        for (int t = 0; t < 8; ++t) {
            H8 b;
            b.h2[0] = xp[t] * yp[0];
            b.h2[1] = xp[t] * yp[1];
            b.h2[2] = xp[t] * yp[2];
            b.h2[3] = xp[t] * yp[3];
            acc = __builtin_amdgcn_mfma_f32_16x16x32_f16(wfrag[t], b.h8, acc, 0, 0, 0);
        }

        // ---- stores: 4 rows, 64B per 16-lane quad ----
        const int f0 = g * 16 + L;
#pragma unroll
        for (int r = 0; r < 4; ++r) {
            const int row = (quad * 4 + r) * FF;
            ob[row + f0] = acc[r];
        }
    }
}

extern "C" void kernel_launch(void* const* d_in, const int* in_sizes, int n_in,
                              void* d_out, int out_size, void* d_ws, size_t ws_size,
                              hipStream_t stream) {
    const float* x   = (const float*)d_in[0];
    const float* y   = (const float*)d_in[1];
    const float* cgc = (const float*)d_in[2];
    float* out = (float*)d_out;

    // 4096 bm x 2 f-halves = 8192 waves: 2048 blocks x 256 threads.
    hipLaunchKernelGGL(tpc_mfma_occ6_kernel, dim3(2048), dim3(256), 0, stream,
                       x, y, cgc, out);
}

// Round 6
// 106.406 us; speedup vs baseline: 1.1503x; 1.0399x over previous
//
#include <hip/hip_runtime.h>

// out[b,m,d,f] = sum_{a,c} x[b,m,a,f] * y[b,m,c,f] * cgc[a,d,c]
// Round 12: R6's LDS/gload_lds structure + counted-vmcnt deep pipeline (T3/T4).
//
// R6 (best, ~23us inferred) drains vmcnt(0) at every __syncthreads -> per-bm
// convoy: the whole block's VMEM queue (prefetch + stores) empties once per
// iteration. This round replaces it with the counted-waitcnt schedule:
//   - BM_PER_BLOCK=8, 512 blocks (2/CU), 3-buffer LDS rotation (48 KB)
//   - STAGE(i+2) issued after compute(i): depth-2 staging, queue never empty
//   - s_waitcnt vmcnt(N) with N counted to leave stage(i+1)+stores in flight
//     (i=0: 4; i=1..6: 12; i=7: 8); raw s_barrier; NO __syncthreads in loop
// Buffer safety: barrier(i) is passed only after all waves completed
// compute(i-1); STAGE(i+2) (writes buf (i+2)%3 == (i-1)%3) is issued after
// that barrier. Data-ready: own slice via vmcnt, others' via their vmcnt +
// the same barrier.
//
// Verified MFMA mapping (R3-R11): A elem j = cgc[2t+qh][L][c0+j],
// B elem j = x[2t+qh][f]*y[c0+j][f], D row=quad*4+r col=L.

typedef __attribute__((ext_vector_type(2))) _Float16 half2v;
typedef __attribute__((ext_vector_type(8))) _Float16 half8;
typedef __attribute__((ext_vector_type(4))) float    floatx4;

#define AA 16
#define FF 128
#define BM_PER_BLOCK 8
#define NBUF 3

union H8 { half2v h2[4]; half8 h8; };

static __device__ __forceinline__ half2v pkrtz(float a, float b) {
    return __builtin_bit_cast(half2v, __builtin_amdgcn_cvt_pkrtz(a, b));
}

static __device__ __forceinline__ void gload_lds16(const float* g, float* l) {
    __builtin_amdgcn_global_load_lds(
        (const __attribute__((address_space(1))) void*)g,
        (__attribute__((address_space(3))) void*)l,
        16, 0, 0);
}

// counted wait + raw barrier; "memory" clobber keeps LDS reads / stores /
// stage intrinsics from crossing (rule #18: sched_barrier after each).
#define WAITB(N) do {                                            \
    asm volatile("s_waitcnt vmcnt(" #N ")" ::: "memory");        \
    __builtin_amdgcn_sched_barrier(0);                           \
    __builtin_amdgcn_s_barrier();                                \
    __builtin_amdgcn_sched_barrier(0);                           \
} while (0)

__global__ __launch_bounds__(256, 2)
void tpc_mfma_vmcnt_kernel(const float* __restrict__ x,
                           const float* __restrict__ y,
                           const float* __restrict__ cgc,
                           float* __restrict__ out) {
    __shared__ float lx[NBUF][AA * FF];   // 3 x 8KB
    __shared__ float ly[NBUF][AA * FF];   // 3 x 8KB

    const int tid  = threadIdx.x;
    const int w    = tid >> 6;         // wave 0..3
    const int lane = tid & 63;
    const int L    = lane & 15;        // A: m(=d); B: n(=f in tile); D: col
    const int quad = lane >> 4;
    const int qh   = quad >> 1;        // a parity
    const int c0   = (quad & 1) * 8;   // c sub-range

    const int bm0 = blockIdx.x * BM_PER_BLOCK;
    const size_t stride = (size_t)(AA * FF);
    const int off = w * 512 + lane * 4;          // this thread's staging slot
    const int f0  = w * 32 + L;                  // wave w owns f-tiles 2w,2w+1

    // stage bm0+i into buffer (i % NBUF): 4 gload_lds16 per wave
    auto STAGE = [&](int i) {
        const float* xb = x + (size_t)(bm0 + i) * stride;
        const float* yb = y + (size_t)(bm0 + i) * stride;
        float* lxd = &lx[i % NBUF][0];
        float* lyd = &ly[i % NBUF][0];
        gload_lds16(xb + off,       lxd + off);
        gload_lds16(xb + off + 256, lxd + off + 256);
        gload_lds16(yb + off,       lyd + off);
        gload_lds16(yb + off + 256, lyd + off + 256);
    };

    // ---- prologue: stage bm0, bm0+1; W-frag build overlaps their latency ----
    STAGE(0);
    STAGE(1);

    half8 wfrag[8];
#pragma unroll
    for (int t = 0; t < 8; ++t) {
        const float* wp = cgc + (2 * t + qh) * (AA * AA) + L * AA + c0;
        const floatx4 w0 = *(const floatx4*)(wp);
        const floatx4 w1 = *(const floatx4*)(wp + 4);
        H8 wa;
        wa.h2[0] = pkrtz(w0.x, w0.y);
        wa.h2[1] = pkrtz(w0.z, w0.w);
        wa.h2[2] = pkrtz(w1.x, w1.y);
        wa.h2[3] = pkrtz(w1.z, w1.w);
        wfrag[t] = wa.h8;
    }

    // compute bm0+i from buffer (i % NBUF), then store (8 dword stores)
    auto COMPUTE = [&](int i) {
        const float* lxc = &lx[i % NBUF][0];
        const float* lyc = &ly[i % NBUF][0];

        float xvA[8], xvB[8], yvA[8], yvB[8];
#pragma unroll
        for (int j = 0; j < 8; ++j) {
            yvA[j] = lyc[(c0 + j) * FF + f0];
            yvB[j] = lyc[(c0 + j) * FF + f0 + 16];
        }
#pragma unroll
        for (int t = 0; t < 8; ++t) {
            xvA[t] = lxc[(2 * t + qh) * FF + f0];
            xvB[t] = lxc[(2 * t + qh) * FF + f0 + 16];
        }

        half2v ypA[4], ypB[4];
#pragma unroll
        for (int jj = 0; jj < 4; ++jj) {
            ypA[jj] = pkrtz(yvA[2 * jj], yvA[2 * jj + 1]);
            ypB[jj] = pkrtz(yvB[2 * jj], yvB[2 * jj + 1]);
        }

        floatx4 acc0 = {0.f, 0.f, 0.f, 0.f};
        floatx4 acc1 = {0.f, 0.f, 0.f, 0.f};
#pragma unroll
        for (int t = 0; t < 8; ++t) {
            half2v xp = pkrtz(xvA[t], xvA[t]);
            H8 b0;
            b0.h2[0] = xp * ypA[0];
            b0.h2[1] = xp * ypA[1];
            b0.h2[2] = xp * ypA[2];
            b0.h2[3] = xp * ypA[3];
            acc0 = __builtin_amdgcn_mfma_f32_16x16x32_f16(wfrag[t], b0.h8, acc0, 0, 0, 0);

            xp = pkrtz(xvB[t], xvB[t]);
            H8 b1;
            b1.h2[0] = xp * ypB[0];
            b1.h2[1] = xp * ypB[1];
            b1.h2[2] = xp * ypB[2];
            b1.h2[3] = xp * ypB[3];
            acc1 = __builtin_amdgcn_mfma_f32_16x16x32_f16(wfrag[t], b1.h8, acc1, 0, 0, 0);
        }

        float* ob = out + (size_t)(bm0 + i) * stride;
#pragma unroll
        for (int r = 0; r < 4; ++r) {
            const int row = (quad * 4 + r) * FF;
            ob[row + f0]      = acc0[r];
            ob[row + f0 + 16] = acc1[r];
        }
    };

    // ---- pipelined main loop: wait(counted) -> barrier -> compute -> stage ----
    // per-wave VMEM per iter: 4 gload_lds (G) + 8 stores (S).
    // i=0:   outstanding allowed G(1)=4            -> vmcnt(4)
    // i=1-6: outstanding allowed S(i-1)+G(i+1)=12  -> vmcnt(12)
    // i=7:   outstanding allowed S(6)=8            -> vmcnt(8)
#define BODY(i, N) do { WAITB(N); COMPUTE(i); if ((i) + 2 < BM_PER_BLOCK) STAGE((i) + 2); } while (0)
    BODY(0, 4);
    BODY(1, 12);
    BODY(2, 12);
    BODY(3, 12);
    BODY(4, 12);
    BODY(5, 12);
    BODY(6, 12);
    BODY(7, 8);
#undef BODY
}

extern "C" void kernel_launch(void* const* d_in, const int* in_sizes, int n_in,
                              void* d_out, int out_size, void* d_ws, size_t ws_size,
                              hipStream_t stream) {
    const float* x   = (const float*)d_in[0];
    const float* y   = (const float*)d_in[1];
    const float* cgc = (const float*)d_in[2];
    float* out = (float*)d_out;

    // 4096 bm / 8 per block = 512 blocks x 256 threads (2 blocks/CU, 48KB LDS each)
    hipLaunchKernelGGL(tpc_mfma_vmcnt_kernel, dim3(512), dim3(256), 0, stream,
                       x, y, cgc, out);
}